// Round 6
// baseline (335.926 us; speedup 1.0000x reference)
//
#include <hip/hip_runtime.h>

#define UU 2048
#define DM 32
#define TB 128   // strip height / tile edge
#define NB 16    // batch
#define NP 3     // pairs
#define NT (UU / TB)        // 16 j-tiles per strip sweep
#define NSTRIP 16           // strips per z
#define ASZ (NB * UU * DM)  // elements per split array = 1,048,576

// workspace layout (float offsets)
#define WS_S1 0                              // (unused, kept for layout)
#define WS_S2 (NP * NB * UU)                 // 98304
#define WS_OO (2 * NP * NB * UU)             // 196608
#define WS_CCA (WS_OO + NP * NB * 2 * DM)    // 199680
#define WS_SPLIT 204800                      // ushort split arrays start here
// total ws bytes = 204800*4 + 6*ASZ*2 = 13,402,112 (~12.8 MB) — required.
// S1 per-strip partials (48*16*2048 floats = 6 MB) live in d_out (8.4 MB),
// fully overwritten by stage4 afterwards.

typedef short short8_t __attribute__((ext_vector_type(8)));
typedef float float4_t __attribute__((ext_vector_type(4)));

#if __has_builtin(__builtin_amdgcn_exp2f)
#define EXP2(x) __builtin_amdgcn_exp2f(x)
#else
#define EXP2(x) exp2f(x)
#endif

// sqrt(log2(e)): scaling BOTH operands by this makes the MFMA dot equal
// log2(e) * (f1.f2), so exp(dot) == 2^(mfma result).
#define SQRT_LOG2E 1.2011224087864498f

// split scaled x into bf16 hi (truncate) + bf16 lo (truncate of remainder).
__device__ inline void split8s(const float4 x0, const float4 x1, short8_t& h,
                               short8_t& lo) {
  float xs[8] = {x0.x, x0.y, x0.z, x0.w, x1.x, x1.y, x1.z, x1.w};
#pragma unroll
  for (int i = 0; i < 8; ++i) {
    float xv = xs[i] * SQRT_LOG2E;
    unsigned u = __float_as_uint(xv);
    h[i] = (short)(u >> 16);
    float hif = __uint_as_float(u & 0xffff0000u);
    lo[i] = (short)(__float_as_uint(xv - hif) >> 16);
  }
}

// ---------------------------------------------------------------------------
// Stage 0: one-time f32 -> (hi,lo) bf16 split of all three embeddings,
// scaled by sqrt(log2 e). Also zeroes the OO atomic accumulator.
// Layout: H + arr*2*ASZ = hi[16][2048][32], +ASZ = lo.  arr: 0=a 1=v 2=l.
// ---------------------------------------------------------------------------
__global__ __launch_bounds__(256) void stage0_prep(
    const float* __restrict__ a, const float* __restrict__ v,
    const float* __restrict__ l, float* __restrict__ ws) {
  const int gid = blockIdx.x * 256 + threadIdx.x;  // 0..393215
  if (gid < (NP * NB * 2 * DM) / 4)
    ((float4*)(ws + WS_OO))[gid] = make_float4(0.f, 0.f, 0.f, 0.f);

  const int per = ASZ / 8;  // 131072 threads per input array
  const int arr = (gid >= per) + (gid >= 2 * per);  // uniform per block
  const float* src = (arr == 0) ? a : (arr == 1) ? v : l;
  const int loc = gid - arr * per;
  const float4* sp = (const float4*)(src + (size_t)loc * 8);
  float4 x0 = sp[0], x1 = sp[1];
  short8_t h, lo;
  split8s(x0, x1, h, lo);
  unsigned short* hq =
      (unsigned short*)(ws + WS_SPLIT) + (size_t)arr * 2 * ASZ + (size_t)loc * 8;
  *(short8_t*)hq = h;
  *(short8_t*)(hq + ASZ) = lo;
}

// ---------------------------------------------------------------------------
// Stage 1 (MFMA bf16x3, barrier-free wave-decoupled): block = (z, i-strip of
// 128 rows).  Wave w owns B-row slice [w*32, w*32+32) of EVERY j-tile:
//  - A strip (128 rows, hi+lo) lives in registers (64 VGPR), loaded once.
//  - B slice streams global->VGPR, double-buffered in EIGHT NAMED short8_t
//    scalars with a hand-written 2-phase loop (rule #20: any runtime-indexed
//    ext_vector array goes to scratch — round 5 proved it: VGPR 84 + 326 MB
//    scratch writes).  All indices below are compile-time.
//  - col sums accumulate in wave-sliced LDS S1L (disjoint, no atomics).
//  - row sums in registers rowp[8][4]; ONE __syncthreads at the end.
// XCD swizzle: 6 z per XCD (48 = 8*6), all 16 strips of a z on one XCD,
// L2 multicasts the shared B stream.  3 blocks/CU, 768 blocks co-resident.
// C/D layout: col=lane&15, row=(lane>>4)*4+reg  [m89-verified].
// ---------------------------------------------------------------------------
__global__ __launch_bounds__(256, 3) void stage1_sums(
    const unsigned short* __restrict__ H, float* __restrict__ S1part,
    float* __restrict__ S2) {
  const int lid = blockIdx.x;          // 0..767 (768 % 8 == 0)
  const int xcd = lid & 7;
  const int r6 = lid >> 3;             // 0..95
  const int z = xcd * 6 + (r6 >> 4);   // 0..47 = p*16+b
  const int strip = r6 & 15;
  const int p = z >> 4, b = z & 15;
  const int i0 = strip * TB;

  const int a1 = (p == 2) ? 1 : 0;  // p0:(a,v) p1:(a,l) p2:(v,l)
  const int a2 = (p == 0) ? 1 : 2;
  const unsigned short* f1h = H + (size_t)a1 * 2 * ASZ + (size_t)b * UU * DM;
  const unsigned short* f2h = H + (size_t)a2 * 2 * ASZ + (size_t)b * UU * DM;

  __shared__ float S1L[UU];      // 8 KiB, wave-sliced col-sum accumulator
  __shared__ float S2L[4][TB];   // 2 KiB, final cross-wave row reduce

  const int t = threadIdx.x;
  const int lane = t & 63, w = t >> 6;
  const int lm = lane & 15, lq = lane >> 4, k0 = lq * 8;

  // zero this wave's S1L slots (jt*128 + w*32 + c) — wave-private, no barrier
#pragma unroll
  for (int m = 0; m < 8; ++m) {
    int jt = m * 2 + (lane >> 5);
    S1L[jt * TB + w * 32 + (lane & 31)] = 0.f;
  }

  // A fragments (hi+lo) for all 8 row-tiles of the strip, straight to VGPR.
  short8_t a_h[8], a_l[8];
#pragma unroll
  for (int rt = 0; rt < 8; ++rt) {
    const unsigned short* ar = f1h + (size_t)(i0 + rt * 16 + lm) * DM + k0;
    a_h[rt] = *(const short8_t*)ar;
    a_l[rt] = *(const short8_t*)(ar + ASZ);
  }

  float rowp[8][4];
#pragma unroll
  for (int rt = 0; rt < 8; ++rt)
#pragma unroll
    for (int r = 0; r < 4; ++r) rowp[rt][r] = 0.f;

  const unsigned short* gb0 = f2h + (size_t)(w * 32 + lm) * DM + k0;

  // named-register B double buffer (set A / set B), hi+lo, 2 ct sub-tiles.
  short8_t bhA0, bhA1, blA0, blA1, bhB0, bhB1, blB0, blB1;

#define LOADB(BH0, BH1, BL0, BL1, jt)                          \
  {                                                            \
    const unsigned short* gb = gb0 + (size_t)(jt)*TB * DM;     \
    BH0 = *(const short8_t*)gb;                                \
    BH1 = *(const short8_t*)(gb + 16 * DM);                    \
    BL0 = *(const short8_t*)(gb + ASZ);                        \
    BL1 = *(const short8_t*)(gb + ASZ + 16 * DM);              \
  }

#define COMPUTE_CT(BH, BL, kk, ct)                                           \
  {                                                                          \
    float colp = 0.f;                                                        \
    _Pragma("unroll") for (int rt = 0; rt < 8; ++rt) {                       \
      float4_t c = {0.f, 0.f, 0.f, 0.f};                                     \
      c = __builtin_amdgcn_mfma_f32_16x16x32_bf16(a_h[rt], BH, c, 0, 0, 0);  \
      c = __builtin_amdgcn_mfma_f32_16x16x32_bf16(a_h[rt], BL, c, 0, 0, 0);  \
      c = __builtin_amdgcn_mfma_f32_16x16x32_bf16(a_l[rt], BH, c, 0, 0, 0);  \
      float e0 = EXP2(c[0]);                                                 \
      float e1 = EXP2(c[1]);                                                 \
      float e2 = EXP2(c[2]);                                                 \
      float e3 = EXP2(c[3]);                                                 \
      rowp[rt][0] += e0;                                                     \
      rowp[rt][1] += e1;                                                     \
      rowp[rt][2] += e2;                                                     \
      rowp[rt][3] += e3;                                                     \
      colp += (e0 + e1) + (e2 + e3);                                         \
    }                                                                        \
    colp += __shfl_xor(colp, 16, 64);                                        \
    colp += __shfl_xor(colp, 32, 64);                                        \
    if (lane < 16) S1L[(kk)*TB + w * 32 + (ct)*16 + lane] += colp;           \
  }

  LOADB(bhA0, bhA1, blA0, blA1, 0);
#pragma unroll 1
  for (int k = 0; k < NT; k += 2) {
    LOADB(bhB0, bhB1, blB0, blB1, k + 1);
    COMPUTE_CT(bhA0, blA0, k, 0);
    COMPUTE_CT(bhA1, blA1, k, 1);
    if (k + 2 < NT) LOADB(bhA0, bhA1, blA0, blA1, k + 2);
    COMPUTE_CT(bhB0, blB0, k + 1, 0);
    COMPUTE_CT(bhB1, blB1, k + 1, 1);
  }
#undef LOADB
#undef COMPUTE_CT

  // Row sums: reduce over the wave's 16 lm columns, park per-wave partials.
#pragma unroll
  for (int rt = 0; rt < 8; ++rt)
#pragma unroll
    for (int r = 0; r < 4; ++r) {
      float vv = rowp[rt][r];
      vv += __shfl_xor(vv, 1, 64);
      vv += __shfl_xor(vv, 2, 64);
      vv += __shfl_xor(vv, 4, 64);
      vv += __shfl_xor(vv, 8, 64);
      if (lm == 0) S2L[w][rt * 16 + lq * 4 + r] = vv;
    }
  __syncthreads();  // the ONLY block-wide barrier

  const size_t base = (size_t)z * UU;
  if (t < TB)
    S2[base + i0 + t] = S2L[0][t] + S2L[1][t] + S2L[2][t] + S2L[3][t];

  // one coalesced per-strip col-sum slab write
  {
    float* dst = S1part + ((size_t)z * NSTRIP + strip) * UU;
#pragma unroll
    for (int m = 0; m < 8; ++m) dst[m * 256 + t] = S1L[m * 256 + t];
  }
}

// ---------------------------------------------------------------------------
// Stage 2: per (pair, b, dir, chunk-of-256-rows) accumulate the 32-vector
//   dir0: O1 += sum_j exp(f1_0 . f2_j)/S1[j] * f2_j   (S1 = sum of 16 partials)
//   dir1: O2 += sum_i exp(f1_i . f2_0)/S2[i] * f1_i
// ---------------------------------------------------------------------------
__global__ __launch_bounds__(256) void stage2_O(
    const float* __restrict__ a, const float* __restrict__ v,
    const float* __restrict__ l, const float* __restrict__ S1part,
    const float* __restrict__ S2, float* __restrict__ OO) {
  const int idx = blockIdx.x;
  const int chunk = idx & 7;
  const int pd = idx >> 3;
  const int dir = pd & 1;
  const int pb = pd >> 1;
  const int p = pb >> 4, b = pb & 15;
  const float* f1 = (p == 2) ? v : a;
  const float* f2 = (p == 0) ? v : l;
  f1 += (size_t)b * UU * DM;
  f2 += (size_t)b * UU * DM;
  const float* qrow = (dir == 0) ? f1 : f2;
  const float* rows = (dir == 0) ? f2 : f1;

  __shared__ float qv[DM];
  __shared__ __align__(16) float rowsL[256 * 36];  // pad 36 -> bank-free
  __shared__ float wL[256];
  __shared__ float wred[8][DM];
  const int t = threadIdx.x;
  if (t < DM) qv[t] = qrow[t];
  __syncthreads();

  const int r = chunk * 256 + t;
  const float4* rp = (const float4*)(rows + (size_t)r * DM);
  float dot = 0.f;
#pragma unroll
  for (int qq = 0; qq < 8; ++qq) {
    float4 x = rp[qq];
    *(float4*)&rowsL[t * 36 + qq * 4] = x;
    dot = fmaf(x.x, qv[4 * qq + 0], dot);
    dot = fmaf(x.y, qv[4 * qq + 1], dot);
    dot = fmaf(x.z, qv[4 * qq + 2], dot);
    dot = fmaf(x.w, qv[4 * qq + 3], dot);
  }
  float den;
  if (dir == 0) {
    const float* sp = S1part + (size_t)pb * NSTRIP * UU + r;
    float s = 0.f;
#pragma unroll
    for (int s16 = 0; s16 < NSTRIP; ++s16) s += sp[(size_t)s16 * UU];
    den = s;
  } else {
    den = S2[(size_t)pb * UU + r];
  }
  wL[t] = __expf(dot) / den;
  __syncthreads();

  const int d = t & 31, sl = t >> 5;
  float acc = 0.f;
#pragma unroll
  for (int k = 0; k < 32; ++k) {
    const int rr = sl * 32 + k;
    acc = fmaf(wL[rr], rowsL[rr * 36 + d], acc);
  }
  wred[sl][d] = acc;
  __syncthreads();
  if (t < DM) {
    float o = 0.f;
#pragma unroll
    for (int s2 = 0; s2 < 8; ++s2) o += wred[s2][t];
    atomicAdd(&OO[(size_t)pd * DM + t], o);
  }
}

// ---------------------------------------------------------------------------
// Stage 3 (1024 threads, one block): Bi = OO*qrow; Ci = tanh(Bi@fc1^T+b)@fc2^T;
// alpha = softmax over batch; CCA[b,:] = sum_k alpha[b,k]*Bi[b,k,:]
// ---------------------------------------------------------------------------
__global__ __launch_bounds__(1024) void stage3_head(
    const float* __restrict__ a, const float* __restrict__ v,
    const float* __restrict__ l, const float* __restrict__ OO,
    const float* __restrict__ fc1w, const float* __restrict__ fc1b,
    const float* __restrict__ fc2w, float* __restrict__ CCA) {
  const int t = threadIdx.x;
  __shared__ float BiL[NB * NP * 64];
  __shared__ float CiS[NB * NP];
  __shared__ float denomk[NP];
  __shared__ float fwL[64 * 65];

#pragma unroll
  for (int it = 0; it < 4; ++it) {
    int m = it * 1024 + t;
    fwL[(m >> 6) * 65 + (m & 63)] = fc1w[m];
  }

#pragma unroll
  for (int iter = 0; iter < 3; ++iter) {
    int m = iter * 1024 + t;  // 0..3071
    int bk = m >> 6;          // b*NP + p
    int h = m & 63;
    int b = bk / NP, p = bk - b * NP;
    int dir = h >> 5, hd = h & 31;
    const float* base = (dir == 0) ? ((p == 2) ? v : a) : ((p == 0) ? v : l);
    float q = base[(size_t)b * UU * DM + hd];
    int pb = p * NB + b;
    BiL[bk * 64 + h] = OO[(pb * 2 + dir) * DM + hd] * q;
  }
  __syncthreads();

  const int h = t & 63;
  const int g = t >> 6;  // 0..15
#pragma unroll
  for (int iter = 0; iter < 3; ++iter) {
    int bk = g + 16 * iter;
    float x = fc1b[h];
#pragma unroll 8
    for (int c = 0; c < 64; ++c)
      x = fmaf(BiL[bk * 64 + c], fwL[h * 65 + c], x);
    float vv = tanhf(x) * fc2w[h];
#pragma unroll
    for (int off = 32; off > 0; off >>= 1) vv += __shfl_down(vv, off, 64);
    if (h == 0) CiS[bk] = vv;
  }
  __syncthreads();

  if (t < NP) {
    float s = 0.f;
    for (int b = 0; b < NB; ++b) s += __expf(CiS[b * NP + t]);
    denomk[t] = s;
  }
  __syncthreads();

  {
    int b = g;
    float s = 0.f;
#pragma unroll
    for (int k = 0; k < NP; ++k)
      s += __expf(CiS[b * NP + k]) / denomk[k] * BiL[(b * NP + k) * 64 + h];
    CCA[b * 64 + h] = s;
  }
}

// ---------------------------------------------------------------------------
// Stage 4: broadcast CCA[b,:] to out[b, u, :] for all u.  float4 stores.
// (Also overwrites the S1part scratch that lived in d_out.)
// ---------------------------------------------------------------------------
__global__ __launch_bounds__(256) void stage4_bcast(
    const float* __restrict__ CCA, float4* __restrict__ out) {
  const int gid = blockIdx.x * 256 + threadIdx.x;  // 0 .. 524287
  const int c4 = gid & 15;
  const int b = gid >> 15;
  const float4* cc = (const float4*)CCA;
  out[gid] = cc[b * 16 + c4];
}

extern "C" void kernel_launch(void* const* d_in, const int* in_sizes, int n_in,
                              void* d_out, int out_size, void* d_ws,
                              size_t ws_size, hipStream_t stream) {
  const float* a = (const float*)d_in[0];
  const float* v = (const float*)d_in[1];
  const float* l = (const float*)d_in[2];
  const float* fc1w = (const float*)d_in[3];
  const float* fc1b = (const float*)d_in[4];
  const float* fc2w = (const float*)d_in[5];
  float* out = (float*)d_out;

  float* ws = (float*)d_ws;
  float* S2 = ws + WS_S2;
  float* OO = ws + WS_OO;
  float* CCA = ws + WS_CCA;
  const unsigned short* H = (const unsigned short*)(ws + WS_SPLIT);
  float* S1part = (float*)d_out;  // 6 MB scratch; stage4 overwrites last

  stage0_prep<<<dim3(1536), 256, 0, stream>>>(a, v, l, ws);
  stage1_sums<<<dim3(NP * NB * NSTRIP), 256, 0, stream>>>(H, S1part, S2);
  stage2_O<<<dim3(NP * NB * 2 * 8), 256, 0, stream>>>(a, v, l, S1part, S2, OO);
  stage3_head<<<dim3(1), 1024, 0, stream>>>(a, v, l, OO, fc1w, fc1b, fc2w,
                                            CCA);
  stage4_bcast<<<dim3(2048), 256, 0, stream>>>(CCA, (float4*)out);
}

// Round 10
// 161.681 us; speedup vs baseline: 2.0777x; 2.0777x over previous
//
#include <hip/hip_runtime.h>

#define UU 2048
#define DM 32
#define TB 128   // tile edge / strip height
#define NB 16    // batch
#define NP 3     // pairs
#define NT (UU / TB)        // 16 j-tiles per strip sweep
#define NSTRIP 16           // strips per z
#define ASZ (NB * UU * DM)  // elements per split array = 1,048,576

// workspace layout (float offsets)
#define WS_S1 0                              // (unused, kept for layout)
#define WS_S2 (NP * NB * UU)                 // 98304
#define WS_OO (2 * NP * NB * UU)             // 196608
#define WS_CCA (WS_OO + NP * NB * 2 * DM)    // 199680
#define WS_SPLIT 204800                      // ushort split arrays start here
// total ws bytes = 204800*4 + 6*ASZ*2 = 13,402,112 (~12.8 MB) — required.
// S1 per-strip partials (48*16*2048 floats = 6 MB) live in d_out (8.4 MB),
// fully overwritten by stage4 afterwards.

typedef short short8_t __attribute__((ext_vector_type(8)));
typedef float float4_t __attribute__((ext_vector_type(4)));

#if __has_builtin(__builtin_amdgcn_exp2f)
#define EXP2(x) __builtin_amdgcn_exp2f(x)
#else
#define EXP2(x) exp2f(x)
#endif

// sqrt(log2(e)): scaling BOTH operands by this makes the MFMA dot equal
// log2(e) * (f1.f2), so exp(dot) == 2^(mfma result).
#define SQRT_LOG2E 1.2011224087864498f

__device__ inline void async16(void* lds, const void* g) {
  __builtin_amdgcn_global_load_lds(
      (const __attribute__((address_space(1))) unsigned int*)g,
      (__attribute__((address_space(3))) unsigned int*)lds, 16, 0, 0);
}

// split scaled x into bf16 hi (truncate) + bf16 lo (truncate of remainder).
__device__ inline void split8s(const float4 x0, const float4 x1, short8_t& h,
                               short8_t& lo) {
  float xs[8] = {x0.x, x0.y, x0.z, x0.w, x1.x, x1.y, x1.z, x1.w};
#pragma unroll
  for (int i = 0; i < 8; ++i) {
    float xv = xs[i] * SQRT_LOG2E;
    unsigned u = __float_as_uint(xv);
    h[i] = (short)(u >> 16);
    float hif = __uint_as_float(u & 0xffff0000u);
    lo[i] = (short)(__float_as_uint(xv - hif) >> 16);
  }
}

// ---------------------------------------------------------------------------
// Stage 0: one-time f32 -> (hi,lo) bf16 split of all three embeddings,
// scaled by sqrt(log2 e). Also zeroes the OO atomic accumulator.
// Layout: H + arr*2*ASZ = hi[16][2048][32], +ASZ = lo.  arr: 0=a 1=v 2=l.
// ---------------------------------------------------------------------------
__global__ __launch_bounds__(256) void stage0_prep(
    const float* __restrict__ a, const float* __restrict__ v,
    const float* __restrict__ l, float* __restrict__ ws) {
  const int gid = blockIdx.x * 256 + threadIdx.x;  // 0..393215
  if (gid < (NP * NB * 2 * DM) / 4)
    ((float4*)(ws + WS_OO))[gid] = make_float4(0.f, 0.f, 0.f, 0.f);

  const int per = ASZ / 8;  // 131072 threads per input array
  const int arr = (gid >= per) + (gid >= 2 * per);  // uniform per block
  const float* src = (arr == 0) ? a : (arr == 1) ? v : l;
  const int loc = gid - arr * per;
  const float4* sp = (const float4*)(src + (size_t)loc * 8);
  float4 x0 = sp[0], x1 = sp[1];
  short8_t h, lo;
  split8s(x0, x1, h, lo);
  unsigned short* hq =
      (unsigned short*)(ws + WS_SPLIT) + (size_t)arr * 2 * ASZ + (size_t)loc * 8;
  *(short8_t*)hq = h;
  *(short8_t*)(hq + ASZ) = lo;
}

// ---------------------------------------------------------------------------
// Stage 1 — R3 structure with ONE __syncthreads per tile (was 2 barriers).
// Block = (z, i-strip of 128 rows); wave w owns rows [w*32,w*32+32);
// sweeps j-tiles 0..15 IN ORDER (16-strip L2 multicast).
// Per tile: [__syncthreads(); stage(k+1); compute(k)].
//   __syncthreads drains vmcnt (tile-k loads landed) AND lgkmcnt (prior
//   tile's ds_reads serviced) before the barrier -> 2-buffer ring is safe.
//   - col sums -> persistent S1L via atomicAdd (ds_add_f32), de-phased by
//     per-wave ct rotation; no per-tile combine, no second barrier.
//   - S2 row sums: waves own DISJOINT rows -> direct global stores
//     (r8/r9 post-mortem: the S2L[4][TB] cross-wave sum read 96/128
//     uninitialized entries per wave — THAT was the corruption, not a
//     staging race).
// LDS 42 KB -> 3 blocks/CU; grid 768 = 3*256 exactly one generation.
// C/D layout: col=lane&15, row=(lane>>4)*4+reg  [m89-verified].
// ---------------------------------------------------------------------------
__global__ __launch_bounds__(256, 3) void stage1_sums(
    const unsigned short* __restrict__ H, float* __restrict__ S1part,
    float* __restrict__ S2) {
  const int lid = blockIdx.x;          // 0..767 (768 % 8 == 0)
  const int xcd = lid & 7;
  const int r6 = lid >> 3;             // 0..95
  const int z = xcd * 6 + (r6 >> 4);   // 0..47 = p*16+b
  const int strip = r6 & 15;
  const int p = z >> 4, b = z & 15;
  const int i0 = strip * TB;

  const int a1 = (p == 2) ? 1 : 0;  // p0:(a,v) p1:(a,l) p2:(v,l)
  const int a2 = (p == 0) ? 1 : 2;
  const unsigned short* f1h = H + (size_t)a1 * 2 * ASZ + (size_t)b * UU * DM;
  const unsigned short* f2h = H + (size_t)a2 * 2 * ASZ + (size_t)b * UU * DM;

  __shared__ __align__(16) unsigned short Bbuf[2][2][TB][DM];  // 32 KiB
  __shared__ float S1L[UU];      // 8 KiB persistent col-sum accumulator

  const int t = threadIdx.x;
  const int lane = t & 63, w = t >> 6;
  const int lm = lane & 15, lq = lane >> 4, k0 = lq * 8;

  // zero the col-sum accumulator (visible after the k=0 __syncthreads)
#pragma unroll
  for (int m = 0; m < 8; ++m) S1L[m * 256 + t] = 0.f;

  // A fragments (hi+lo), 2 row-tiles per wave — the R3-proven footprint.
  short8_t a_h[2], a_l[2];
  {
    const unsigned short* ar = f1h + (size_t)(i0 + w * 32 + lm) * DM + k0;
    a_h[0] = *(const short8_t*)ar;
    a_h[1] = *(const short8_t*)(ar + 16 * DM);
    a_l[0] = *(const short8_t*)(ar + ASZ);
    a_l[1] = *(const short8_t*)(ar + ASZ + 16 * DM);
  }

  float rowp[2][4];
#pragma unroll
  for (int rt = 0; rt < 2; ++rt)
#pragma unroll
    for (int r = 0; r < 4; ++r) rowp[rt][r] = 0.f;

  // wave w stages rows [w*32, w*32+32) of hi and lo: 4 async16 per wave.
  auto stageB = [&](int buf, int jt) {
    const unsigned short* gh = f2h + (size_t)(jt * TB + w * 32) * DM + lane * 8;
    async16(&Bbuf[buf][0][w * 32][0], gh);
    async16(&Bbuf[buf][0][w * 32 + 16][0], gh + 16 * DM);
    async16(&Bbuf[buf][1][w * 32][0], gh + ASZ);
    async16(&Bbuf[buf][1][w * 32 + 16][0], gh + ASZ + 16 * DM);
  };

  stageB(0, 0);

#pragma unroll 1
  for (int k = 0; k < NT; ++k) {
    // full drain (vm: tile-k loads landed; lgkm: prior-tile ds_reads
    // serviced) + barrier.  The ONE sync point per tile.
    __syncthreads();
    if (k + 1 < NT) stageB((k + 1) & 1, k + 1);  // flies under compute(k)
    const int buf = k & 1;
#pragma unroll
    for (int c8 = 0; c8 < 8; ++c8) {
      const int ct = (c8 + w * 2) & 7;  // de-phase waves' LDS adds/reads
      short8_t b_h = *(const short8_t*)&Bbuf[buf][0][ct * 16 + lm][k0];
      short8_t b_l = *(const short8_t*)&Bbuf[buf][1][ct * 16 + lm][k0];
      float colp = 0.f;
#pragma unroll
      for (int rt = 0; rt < 2; ++rt) {
        float4_t c = {0.f, 0.f, 0.f, 0.f};
        c = __builtin_amdgcn_mfma_f32_16x16x32_bf16(a_h[rt], b_h, c, 0, 0, 0);
        c = __builtin_amdgcn_mfma_f32_16x16x32_bf16(a_h[rt], b_l, c, 0, 0, 0);
        c = __builtin_amdgcn_mfma_f32_16x16x32_bf16(a_l[rt], b_h, c, 0, 0, 0);
        float e0 = EXP2(c[0]);
        float e1 = EXP2(c[1]);
        float e2 = EXP2(c[2]);
        float e3 = EXP2(c[3]);
        rowp[rt][0] += e0;
        rowp[rt][1] += e1;
        rowp[rt][2] += e2;
        rowp[rt][3] += e3;
        colp += (e0 + e1) + (e2 + e3);
      }
      // col sum over this wave's 32 rows -> ds_add_f32 into S1L
      colp += __shfl_xor(colp, 16, 64);
      colp += __shfl_xor(colp, 32, 64);
      if (lane < 16) atomicAdd(&S1L[k * TB + ct * 16 + lane], colp);
    }
  }

  // S2 row sums: reduce over the wave's 16 lm columns; waves own disjoint
  // rows -> direct global store, no cross-wave combine (r9 bugfix).
  const size_t base = (size_t)z * UU;
#pragma unroll
  for (int rt = 0; rt < 2; ++rt)
#pragma unroll
    for (int r = 0; r < 4; ++r) {
      float vv = rowp[rt][r];
      vv += __shfl_xor(vv, 1, 64);
      vv += __shfl_xor(vv, 2, 64);
      vv += __shfl_xor(vv, 4, 64);
      vv += __shfl_xor(vv, 8, 64);
      if (lm == 0) S2[base + i0 + w * 32 + rt * 16 + lq * 4 + r] = vv;
    }

  __syncthreads();  // drain all waves' ds_adds before reading S1L

  // one coalesced per-strip col-sum slab write
  {
    float* dst = S1part + ((size_t)z * NSTRIP + strip) * UU;
#pragma unroll
    for (int m = 0; m < 8; ++m) dst[m * 256 + t] = S1L[m * 256 + t];
  }
}

// ---------------------------------------------------------------------------
// Stage 2: per (pair, b, dir, chunk-of-256-rows) accumulate the 32-vector
//   dir0: O1 += sum_j exp(f1_0 . f2_j)/S1[j] * f2_j   (S1 = sum of 16 partials)
//   dir1: O2 += sum_i exp(f1_i . f2_0)/S2[i] * f1_i
// ---------------------------------------------------------------------------
__global__ __launch_bounds__(256) void stage2_O(
    const float* __restrict__ a, const float* __restrict__ v,
    const float* __restrict__ l, const float* __restrict__ S1part,
    const float* __restrict__ S2, float* __restrict__ OO) {
  const int idx = blockIdx.x;
  const int chunk = idx & 7;
  const int pd = idx >> 3;
  const int dir = pd & 1;
  const int pb = pd >> 1;
  const int p = pb >> 4, b = pb & 15;
  const float* f1 = (p == 2) ? v : a;
  const float* f2 = (p == 0) ? v : l;
  f1 += (size_t)b * UU * DM;
  f2 += (size_t)b * UU * DM;
  const float* qrow = (dir == 0) ? f1 : f2;
  const float* rows = (dir == 0) ? f2 : f1;

  __shared__ float qv[DM];
  __shared__ __align__(16) float rowsL[256 * 36];  // pad 36 -> bank-free
  __shared__ float wL[256];
  __shared__ float wred[8][DM];
  const int t = threadIdx.x;
  if (t < DM) qv[t] = qrow[t];
  __syncthreads();

  const int r = chunk * 256 + t;
  const float4* rp = (const float4*)(rows + (size_t)r * DM);
  float dot = 0.f;
#pragma unroll
  for (int qq = 0; qq < 8; ++qq) {
    float4 x = rp[qq];
    *(float4*)&rowsL[t * 36 + qq * 4] = x;
    dot = fmaf(x.x, qv[4 * qq + 0], dot);
    dot = fmaf(x.y, qv[4 * qq + 1], dot);
    dot = fmaf(x.z, qv[4 * qq + 2], dot);
    dot = fmaf(x.w, qv[4 * qq + 3], dot);
  }
  float den;
  if (dir == 0) {
    const float* sp = S1part + (size_t)pb * NSTRIP * UU + r;
    float s = 0.f;
#pragma unroll
    for (int s16 = 0; s16 < NSTRIP; ++s16) s += sp[(size_t)s16 * UU];
    den = s;
  } else {
    den = S2[(size_t)pb * UU + r];
  }
  wL[t] = __expf(dot) / den;
  __syncthreads();

  const int d = t & 31, sl = t >> 5;
  float acc = 0.f;
#pragma unroll
  for (int k = 0; k < 32; ++k) {
    const int rr = sl * 32 + k;
    acc = fmaf(wL[rr], rowsL[rr * 36 + d], acc);
  }
  wred[sl][d] = acc;
  __syncthreads();
  if (t < DM) {
    float o = 0.f;
#pragma unroll
    for (int s2 = 0; s2 < 8; ++s2) o += wred[s2][t];
    atomicAdd(&OO[(size_t)pd * DM + t], o);
  }
}

// ---------------------------------------------------------------------------
// Stage 3 (1024 threads, one block): Bi = OO*qrow; Ci = tanh(Bi@fc1^T+b)@fc2^T;
// alpha = softmax over batch; CCA[b,:] = sum_k alpha[b,k]*Bi[b,k,:]
// ---------------------------------------------------------------------------
__global__ __launch_bounds__(1024) void stage3_head(
    const float* __restrict__ a, const float* __restrict__ v,
    const float* __restrict__ l, const float* __restrict__ OO,
    const float* __restrict__ fc1w, const float* __restrict__ fc1b,
    const float* __restrict__ fc2w, float* __restrict__ CCA) {
  const int t = threadIdx.x;
  __shared__ float BiL[NB * NP * 64];
  __shared__ float CiS[NB * NP];
  __shared__ float denomk[NP];
  __shared__ float fwL[64 * 65];

#pragma unroll
  for (int it = 0; it < 4; ++it) {
    int m = it * 1024 + t;
    fwL[(m >> 6) * 65 + (m & 63)] = fc1w[m];
  }

#pragma unroll
  for (int iter = 0; iter < 3; ++iter) {
    int m = iter * 1024 + t;  // 0..3071
    int bk = m >> 6;          // b*NP + p
    int h = m & 63;
    int b = bk / NP, p = bk - b * NP;
    int dir = h >> 5, hd = h & 31;
    const float* base = (dir == 0) ? ((p == 2) ? v : a) : ((p == 0) ? v : l);
    float q = base[(size_t)b * UU * DM + hd];
    int pb = p * NB + b;
    BiL[bk * 64 + h] = OO[(pb * 2 + dir) * DM + hd] * q;
  }
  __syncthreads();

  const int h = t & 63;
  const int g = t >> 6;  // 0..15
#pragma unroll
  for (int iter = 0; iter < 3; ++iter) {
    int bk = g + 16 * iter;
    float x = fc1b[h];
#pragma unroll 8
    for (int c = 0; c < 64; ++c)
      x = fmaf(BiL[bk * 64 + c], fwL[h * 65 + c], x);
    float vv = tanhf(x) * fc2w[h];
#pragma unroll
    for (int off = 32; off > 0; off >>= 1) vv += __shfl_down(vv, off, 64);
    if (h == 0) CiS[bk] = vv;
  }
  __syncthreads();

  if (t < NP) {
    float s = 0.f;
    for (int b = 0; b < NB; ++b) s += __expf(CiS[b * NP + t]);
    denomk[t] = s;
  }
  __syncthreads();

  {
    int b = g;
    float s = 0.f;
#pragma unroll
    for (int k = 0; k < NP; ++k)
      s += __expf(CiS[b * NP + k]) / denomk[k] * BiL[(b * NP + k) * 64 + h];
    CCA[b * 64 + h] = s;
  }
}

// ---------------------------------------------------------------------------
// Stage 4: broadcast CCA[b,:] to out[b, u, :] for all u.  float4 stores.
// (Also overwrites the S1part scratch that lived in d_out.)
// ---------------------------------------------------------------------------
__global__ __launch_bounds__(256) void stage4_bcast(
    const float* __restrict__ CCA, float4* __restrict__ out) {
  const int gid = blockIdx.x * 256 + threadIdx.x;  // 0 .. 524287
  const int c4 = gid & 15;
  const int b = gid >> 15;
  const float4* cc = (const float4*)CCA;
  out[gid] = cc[b * 16 + c4];
}

extern "C" void kernel_launch(void* const* d_in, const int* in_sizes, int n_in,
                              void* d_out, int out_size, void* d_ws,
                              size_t ws_size, hipStream_t stream) {
  const float* a = (const float*)d_in[0];
  const float* v = (const float*)d_in[1];
  const float* l = (const float*)d_in[2];
  const float* fc1w = (const float*)d_in[3];
  const float* fc1b = (const float*)d_in[4];
  const float* fc2w = (const float*)d_in[5];
  float* out = (float*)d_out;

  float* ws = (float*)d_ws;
  float* S2 = ws + WS_S2;
  float* OO = ws + WS_OO;
  float* CCA = ws + WS_CCA;
  const unsigned short* H = (const unsigned short*)(ws + WS_SPLIT);
  float* S1part = (float*)d_out;  // 6 MB scratch; stage4 overwrites last

  stage0_prep<<<dim3(1536), 256, 0, stream>>>(a, v, l, ws);
  stage1_sums<<<dim3(NP * NB * NSTRIP), 256, 0, stream>>>(H, S1part, S2);
  stage2_O<<<dim3(NP * NB * 2 * 8), 256, 0, stream>>>(a, v, l, S1part, S2, OO);
  stage3_head<<<dim3(1), 1024, 0, stream>>>(a, v, l, OO, fc1w, fc1b, fc2w,
                                            CCA);
  stage4_bcast<<<dim3(2048), 256, 0, stream>>>(CCA, (float4*)out);
}